// Round 6
// baseline (717.854 us; speedup 1.0000x reference)
//
#include <hip/hip_runtime.h>

#define DIM 1024
#define SEQ 2048
#define HID 128
#define HEADS 8
#define DECAYC 4
#define CHUNK 32
#define NCH (SEQ / CHUNK)  // 64
#define BK 32
#define NT (DIM / BK)      // 32 K-tiles

typedef __bf16 bf16x8 __attribute__((ext_vector_type(8)));
typedef float f32x4 __attribute__((ext_vector_type(4)));
typedef unsigned short u16x4 __attribute__((ext_vector_type(4)));

__device__ __forceinline__ unsigned short f2bf(float f) {
  union { float f; unsigned u; } v; v.f = f;
  unsigned r = v.u + 0x7fffu + ((v.u >> 16) & 1u);
  return (unsigned short)(r >> 16);
}
__device__ __forceinline__ float bf2f(unsigned short u) {
  union { unsigned u; float f; } v; v.u = ((unsigned)u) << 16;
  return v.f;
}

typedef __attribute__((address_space(1))) const unsigned int* g_u32p;
typedef __attribute__((address_space(3))) unsigned int* l_u32p;

__device__ __forceinline__ void async_ld16(const unsigned short* g, unsigned short* l) {
  __builtin_amdgcn_global_load_lds((g_u32p)g, (l_u32p)l, 16, 0, 0);
}

// ---------------- fp32 -> bf16 convert ----------------
__global__ void convertk(const float* __restrict__ in, unsigned short* __restrict__ out, int n) {
  int i = blockIdx.x * 256 + threadIdx.x;
  if (i < n) out[i] = f2bf(in[i]);
}

// ------------- x (B,E,T) f32 -> xT (B,T,E) bf16 -------------
__global__ __launch_bounds__(256) void transpose_x(const float* __restrict__ x,
                                                   unsigned short* __restrict__ xT) {
  __shared__ float tile[64][65];
  const int b = blockIdx.z;
  const int e0 = blockIdx.x * 64;
  const int t0 = blockIdx.y * 64;
  const int tr = threadIdx.x >> 6;
  const int tc = threadIdx.x & 63;
  const float* xp = x + ((size_t)b * DIM + e0) * SEQ + t0;
#pragma unroll
  for (int i = 0; i < 16; ++i) {
    int e = i * 4 + tr;
    tile[e][tc] = xp[(size_t)e * SEQ + tc];
  }
  __syncthreads();
  unsigned short* op = xT + ((size_t)b * SEQ + t0) * DIM + e0;
#pragma unroll
  for (int i = 0; i < 16; ++i) {
    int t = i * 4 + tr;
    op[(size_t)t * DIM + tc] = f2bf(tile[tc][t]);
  }
}

// ------------- 256x256 NT GEMM, BK=32, 2 blocks/CU -------------
// C[m][n] = sum_k A[m][k]*B[n][k] + bias.  A,B bf16 k-contig (lda=ldb=DIM=K).
// 8 waves (2M x 4N), per-wave 128x64. LDS 64KB: [2 buf][A 16KB | B 16KB].
// Per tile: p0 {4 A-reads + 4 B-reads, stage A(t+1), 16 MFMA},
//           p1 {4 A-reads (B held in regs), stage B(t+1), 16 MFMA},
//           vmcnt(0) + single barrier.
// Swizzle (64B rows): byte ^= ((row>>1)&3)<<4 (HW-verified in R4, 0 conflicts).
template <int C_BF16, int BIAS_ROW, int MODE>
__global__ __launch_bounds__(512, 4) void gemm256(const unsigned short* __restrict__ A,
                                                  const unsigned short* __restrict__ B,
                                                  void* __restrict__ Cv,
                                                  const float* __restrict__ bias,
                                                  int ldc, long sB, long sC) {
  __shared__ unsigned short lds[32768];  // 64 KiB

  int m0, n0, z;
  if constexpr (MODE == 1) {
    m0 = (blockIdx.x >> 2) * 256;
    n0 = (blockIdx.x & 3) * 256;
    z = 0;
  } else {
    z = blockIdx.x >> 5;
    m0 = ((blockIdx.x >> 3) & 3) * 256;
    n0 = (blockIdx.x & 7) * 256;
  }
  B += (size_t)sB * z;

  const int tid = threadIdx.x;
  const int lane = tid & 63;
  const int w = tid >> 6;
  const int wm = w >> 2;  // 0..1
  const int wn = w & 3;   // 0..3

  // ---- staging source pointers (inverse-swizzled): sp[op][j] ----
  const unsigned short* sp[2][2];
#pragma unroll
  for (int j = 0; j < 2; ++j) {
    int c = (w * 2 + j) * 1024 + lane * 16;  // dest byte within 16KB region
    int cs = c ^ (((c >> 7) & 3) << 4);      // inverse swizzle (involution)
    int row = cs >> 6;                       // 0..255
    int colel = (cs & 63) >> 1;              // 0..31 elements
    sp[0][j] = A + (size_t)(m0 + row) * DIM + colel;
    sp[1][j] = B + (size_t)(n0 + row) * DIM + colel;
  }

  // ---- fragment read offsets (swizzled, ushort idx within 16KB region) ----
  const int r15 = lane & 15;
  const int hi = lane >> 4;
  const int rsw = ((r15 >> 1) & 3) << 4;
  int aoff[8], boff[4];
#pragma unroll
  for (int fi = 0; fi < 8; ++fi)
    aoff[fi] = (((wm * 128 + fi * 16 + r15) * 64 + hi * 16) ^ rsw) >> 1;
#pragma unroll
  for (int fj = 0; fj < 4; ++fj)
    boff[fj] = (((wn * 64 + fj * 16 + r15) * 64 + hi * 16) ^ rsw) >> 1;

  f32x4 acc[8][4] = {};

  // stage one operand (op: 0=A,1=B) of K-tile tgt into buffer dd
#define STG(dd, op, tgt)                                                       \
  {                                                                            \
    unsigned short* dst_ =                                                     \
        (unsigned short*)lds + (dd) * 16384 + (op) * 8192 + w * 1024;          \
    async_ld16(sp[op][0] + (size_t)(tgt) * BK, dst_);                          \
    async_ld16(sp[op][1] + (size_t)(tgt) * BK, dst_ + 512);                    \
  }

  // prologue: stage tile 0 into buf 0
  STG(0, 0, 0);
  STG(0, 1, 0);
  asm volatile("s_waitcnt vmcnt(0)" ::: "memory");
  __builtin_amdgcn_s_barrier();

#pragma unroll 2
  for (int t = 0; t < NT; ++t) {
    const int d = t & 1;
    const unsigned short* lbA = (const unsigned short*)lds + d * 16384;
    const unsigned short* lbB = lbA + 8192;
    bf16x8 af[4], bfr[4];
    // ---- phase 0: fi 0..3 ----
#pragma unroll
    for (int i = 0; i < 4; ++i) af[i] = *(const bf16x8*)&lbA[aoff[i]];
#pragma unroll
    for (int j = 0; j < 4; ++j) bfr[j] = *(const bf16x8*)&lbB[boff[j]];
    if (t + 1 < NT) STG(d ^ 1, 0, t + 1);  // buf d^1 dead since last barrier
    asm volatile("s_waitcnt lgkmcnt(0)" ::: "memory");
    __builtin_amdgcn_sched_barrier(0);
    __builtin_amdgcn_s_setprio(1);
#pragma unroll
    for (int i = 0; i < 4; ++i)
#pragma unroll
      for (int j = 0; j < 4; ++j)
        acc[i][j] = __builtin_amdgcn_mfma_f32_16x16x32_bf16(af[i], bfr[j], acc[i][j], 0, 0, 0);
    __builtin_amdgcn_s_setprio(0);
    // ---- phase 1: fi 4..7 (B frags held in regs) ----
#pragma unroll
    for (int i = 0; i < 4; ++i) af[i] = *(const bf16x8*)&lbA[aoff[4 + i]];
    if (t + 1 < NT) STG(d ^ 1, 1, t + 1);
    asm volatile("s_waitcnt lgkmcnt(0)" ::: "memory");
    __builtin_amdgcn_sched_barrier(0);
    __builtin_amdgcn_s_setprio(1);
#pragma unroll
    for (int i = 0; i < 4; ++i)
#pragma unroll
      for (int j = 0; j < 4; ++j)
        acc[4 + i][j] =
            __builtin_amdgcn_mfma_f32_16x16x32_bf16(af[i], bfr[j], acc[4 + i][j], 0, 0, 0);
    __builtin_amdgcn_s_setprio(0);
    // ---- tile boundary: per-wave drain of t+1 stages, then sync ----
    if (t + 1 < NT) asm volatile("s_waitcnt vmcnt(0)" ::: "memory");
    __builtin_amdgcn_s_barrier();
  }
#undef STG

  // ---- epilogue: D mapping col=lane&15, row=(lane>>4)*4+q ----
  const int or0 = hi * 4;
#pragma unroll
  for (int fi = 0; fi < 8; ++fi) {
#pragma unroll
    for (int fj = 0; fj < 4; ++fj) {
      const int col = n0 + wn * 64 + fj * 16 + r15;
      const int rowb = m0 + wm * 128 + fi * 16 + or0;
      float cb = BIAS_ROW ? 0.0f : bias[col];
#pragma unroll
      for (int q = 0; q < 4; ++q) {
        const int row = rowb + q;
        float v = acc[fi][fj][q] + (BIAS_ROW ? bias[row] : cb);
        if constexpr (C_BF16) {
          ((unsigned short*)Cv)[(size_t)sC * z + (size_t)row * ldc + col] = f2bf(v);
        } else {
          ((float*)Cv)[(size_t)sC * z + (size_t)row * ldc + col] = v;
        }
      }
    }
  }
}

// ------------- chunked mixer scan -------------
__global__ __launch_bounds__(256) void scan_carry(const unsigned short* __restrict__ proj,
                                                  float* __restrict__ carry,
                                                  const float* __restrict__ mix_w,
                                                  const float* __restrict__ decay_v) {
  const int b = blockIdx.x >> 6;
  const int c = blockIdx.x & (NCH - 1);
  const int n0 = threadIdx.x * 4;
  const int h = n0 >> 7;
  const float d = fminf(fmaxf(decay_v[h], 0.9f), 1.0f);
  const float r = powf(d, 1.0f / (float)DECAYC);
  const bool colrep = h < (HEADS / 2);
  const u16x4* p = (const u16x4*)(proj + ((size_t)(b * SEQ + c * CHUNK)) * DIM + n0);
  const float* mw = mix_w + h * SEQ + c * CHUNK;
  float s0 = 0.f, s1 = 0.f, s2 = 0.f, s3 = 0.f;
#pragma unroll 8
  for (int t = 0; t < CHUNK; ++t) {
    u16x4 v = p[t * (DIM / 4)];
    float wi = colrep ? 1.0f : mw[t];
    s0 = s0 * r + bf2f(v[0]) * wi;
    s1 = s1 * r + bf2f(v[1]) * wi;
    s2 = s2 * r + bf2f(v[2]) * wi;
    s3 = s3 * r + bf2f(v[3]) * wi;
  }
  f32x4 out = {s0, s1, s2, s3};
  *(f32x4*)(carry + ((size_t)(b * NCH + c)) * DIM + n0) = out;
}

__global__ __launch_bounds__(256) void scan_prefix(float* __restrict__ carry,
                                                   const float* __restrict__ decay_v) {
  const int idx = blockIdx.x * 256 + threadIdx.x;
  const int b = idx >> 10;
  const int n = idx & 1023;
  const int h = n >> 7;
  const float d = fminf(fmaxf(decay_v[h], 0.9f), 1.0f);
  const float r = powf(d, 1.0f / (float)DECAYC);
  const float rL = powf(r, (float)CHUNK);
  float P = 0.0f;
  for (int c = 0; c < NCH; ++c) {
    float* p = carry + ((size_t)(b * NCH + c)) * DIM + n;
    float cc = *p;
    *p = P;
    P = rL * P + cc;
  }
}

__global__ __launch_bounds__(256) void scan_apply(const unsigned short* __restrict__ proj,
                                                  unsigned short* __restrict__ hidden,
                                                  const float* __restrict__ carry,
                                                  const float* __restrict__ mix_w,
                                                  const float* __restrict__ mix_b,
                                                  const float* __restrict__ decay_v) {
  const int b = blockIdx.x >> 6;
  const int c = blockIdx.x & (NCH - 1);
  const int n0 = threadIdx.x * 4;
  const int h = n0 >> 7;
  const float d = fminf(fmaxf(decay_v[h], 0.9f), 1.0f);
  const float r = powf(d, 1.0f / (float)DECAYC);
  const bool colrep = h < (HEADS / 2);
  const size_t base = ((size_t)(b * SEQ + c * CHUNK)) * DIM + n0;
  const u16x4* p = (const u16x4*)(proj + base);
  u16x4* o = (u16x4*)(hidden + base);
  const float* mw = mix_w + h * SEQ + c * CHUNK;
  const float* mb = mix_b + h * SEQ + c * CHUNK;
  f32x4 ci = *(const f32x4*)(carry + ((size_t)(b * NCH + c)) * DIM + n0);
  float s0 = ci[0], s1 = ci[1], s2 = ci[2], s3 = ci[3];
#pragma unroll 8
  for (int t = 0; t < CHUNK; ++t) {
    u16x4 v = p[t * (DIM / 4)];
    float wv = mw[t];
    float wi = colrep ? 1.0f : wv;
    float wo = colrep ? wv : 1.0f;
    float bb = mb[t];
    s0 = s0 * r + bf2f(v[0]) * wi;
    s1 = s1 * r + bf2f(v[1]) * wi;
    s2 = s2 * r + bf2f(v[2]) * wi;
    s3 = s3 * r + bf2f(v[3]) * wi;
    u16x4 ov;
    ov[0] = f2bf(s0 * wo + bb);
    ov[1] = f2bf(s1 * wo + bb);
    ov[2] = f2bf(s2 * wo + bb);
    ov[3] = f2bf(s3 * wo + bb);
    o[t * (DIM / 4)] = ov;
  }
}

extern "C" void kernel_launch(void* const* d_in, const int* in_sizes, int n_in,
                              void* d_out, int out_size, void* d_ws, size_t ws_size,
                              hipStream_t stream) {
  const float* x = (const float*)d_in[0];
  const float* proj_w = (const float*)d_in[1];
  const float* proj_b = (const float*)d_in[2];
  const float* mix_w = (const float*)d_in[3];
  const float* mix_b = (const float*)d_in[4];
  const float* decay_v = (const float*)d_in[5];
  const float* out_w = (const float*)d_in[6];
  const float* out_b = (const float*)d_in[7];

  char* ws = (char*)d_ws;
  unsigned short* xT = (unsigned short*)ws;                // 33.5 MB (B*T, E) bf16
  unsigned short* proj = (unsigned short*)(ws + 33554432); // 33.5 MB (B*T, N) bf16
  unsigned short* W1 = (unsigned short*)(ws + 67108864);   // 2 MB (dead after GEMM1)
  unsigned short* W2 = (unsigned short*)(ws + 69206016);   // 2 MB
  unsigned short* hidden = xT;                             // reuse: xT dead after GEMM1
  float* carryf = (float*)(ws + 67108864);                 // 2 MB, overlaps W1 (dead)

  const int NW = DIM * DIM;
  convertk<<<dim3((NW + 255) / 256), 256, 0, stream>>>(proj_w, W1, NW);
  convertk<<<dim3((NW + 255) / 256), 256, 0, stream>>>(out_w, W2, NW);
  transpose_x<<<dim3(16, 32, 8), 256, 0, stream>>>(x, xT);

  // GEMM1: proj[(b,t)][n] = sum_e xT[(b,t)][e] * W1[n][e] + proj_b[n]
  gemm256<1, 0, 1><<<dim3(256), 512, 0, stream>>>(xT, W1, proj, proj_b, DIM, 0L, 0L);

  // chunked mixer scan
  scan_carry<<<dim3(8 * NCH), 256, 0, stream>>>(proj, carryf, mix_w, decay_v);
  scan_prefix<<<dim3(8192 / 256), 256, 0, stream>>>(carryf, decay_v);
  scan_apply<<<dim3(8 * NCH), 256, 0, stream>>>(proj, hidden, carryf, mix_w, mix_b, decay_v);

  // GEMM2 (per batch): out[b][i][s] = sum_k W2[i][k]*hidden[b][s][k] + out_b[i]
  gemm256<0, 1, 2><<<dim3(256), 512, 0, stream>>>(W2, hidden, d_out, out_b, SEQ,
                                                  (long)SEQ * DIM, (long)DIM * SEQ);
}

// Round 7
// 125.057 us; speedup vs baseline: 5.7402x; 5.7402x over previous
//
#include <hip/hip_runtime.h>

#define DIM 1024
#define SEQ 2048
#define HID 128
#define HEADS 8
#define DECAYC 4
#define CHUNK 32
#define NCH (SEQ / CHUNK)  // 64
#define BK 64
#define NT (DIM / BK)      // 16 K-tiles

typedef __bf16 bf16x8 __attribute__((ext_vector_type(8)));
typedef float f32x4 __attribute__((ext_vector_type(4)));
typedef unsigned short u16x4 __attribute__((ext_vector_type(4)));

__device__ __forceinline__ unsigned short f2bf(float f) {
  union { float f; unsigned u; } v; v.f = f;
  unsigned r = v.u + 0x7fffu + ((v.u >> 16) & 1u);
  return (unsigned short)(r >> 16);
}
__device__ __forceinline__ float bf2f(unsigned short u) {
  union { unsigned u; float f; } v; v.u = ((unsigned)u) << 16;
  return v.f;
}

typedef __attribute__((address_space(1))) const unsigned int* g_u32p;
typedef __attribute__((address_space(3))) unsigned int* l_u32p;

__device__ __forceinline__ void async_ld16(const unsigned short* g, unsigned short* l) {
  __builtin_amdgcn_global_load_lds((g_u32p)g, (l_u32p)l, 16, 0, 0);
}

// ---------------- fp32 -> bf16 convert (both weights, one launch) ----------------
__global__ void convertk2(const float* __restrict__ in0, unsigned short* __restrict__ out0,
                          const float* __restrict__ in1, unsigned short* __restrict__ out1,
                          int n) {
  int i = blockIdx.x * 256 + threadIdx.x;
  if (i < n) {
    out0[i] = f2bf(in0[i]);
    out1[i] = f2bf(in1[i]);
  }
}

// ------------- x (B,E,T) f32 -> xT (B,T,E) bf16 -------------
__global__ __launch_bounds__(256) void transpose_x(const float* __restrict__ x,
                                                   unsigned short* __restrict__ xT) {
  __shared__ float tile[64][65];
  const int b = blockIdx.z;
  const int e0 = blockIdx.x * 64;
  const int t0 = blockIdx.y * 64;
  const int tr = threadIdx.x >> 6;
  const int tc = threadIdx.x & 63;
  const float* xp = x + ((size_t)b * DIM + e0) * SEQ + t0;
#pragma unroll
  for (int i = 0; i < 16; ++i) {
    int e = i * 4 + tr;
    tile[e][tc] = xp[(size_t)e * SEQ + tc];
  }
  __syncthreads();
  unsigned short* op = xT + ((size_t)b * SEQ + t0) * DIM + e0;
#pragma unroll
  for (int i = 0; i < 16; ++i) {
    int t = i * 4 + tr;
    op[(size_t)t * DIM + tc] = f2bf(tile[tc][t]);
  }
}

// ------------- 256x256 8-phase pipelined NT GEMM -------------
// VAR=0: exact R4 schedule (proven 42 us).  VAR=1: B-fragments read once per
// ks and held in regs across the two fiH phases (32 -> 24 ds_read/tile).
template <int C_BF16, int BIAS_ROW, int MODE, int VAR>
__global__ __launch_bounds__(512, 2) void gemm256(const unsigned short* __restrict__ A,
                                                  const unsigned short* __restrict__ B,
                                                  void* __restrict__ Cv,
                                                  const float* __restrict__ bias,
                                                  int ldc, long sB, long sC) {
  __shared__ unsigned short lds[65536];  // 128 KiB

  int m0, n0, z;
  if constexpr (MODE == 1) {
    m0 = (blockIdx.x >> 2) * 256;
    n0 = (blockIdx.x & 3) * 256;
    z = 0;
  } else {
    z = blockIdx.x >> 5;
    m0 = ((blockIdx.x >> 3) & 3) * 256;
    n0 = (blockIdx.x & 7) * 256;
  }
  B += (size_t)sB * z;

  const int tid = threadIdx.x;
  const int lane = tid & 63;
  const int w = tid >> 6;
  const int wm = w >> 2;  // 0..1
  const int wn = w & 3;   // 0..3

  // ---- staging source pointers (inverse-swizzled): sp[op][kh][j] ----
  const unsigned short* sp[2][2][2];
#pragma unroll
  for (int j = 0; j < 2; ++j) {
    int c = (w * 2 + j) * 1024 + lane * 16;     // dest byte within 16KB half
    int cs = c ^ (((c >> 7) & 3) << 4);         // inverse swizzle (involution)
    int row = cs >> 6;                          // 0..255
    int colel = (cs & 63) >> 1;                 // 0..31 elements
#pragma unroll
    for (int kh = 0; kh < 2; ++kh) {
      sp[0][kh][j] = A + (size_t)(m0 + row) * DIM + kh * 32 + colel;
      sp[1][kh][j] = B + (size_t)(n0 + row) * DIM + kh * 32 + colel;
    }
  }

  // ---- fragment read offsets (swizzled, ushort index incl. op/kh base) ----
  const int r15 = lane & 15;
  const int hi = lane >> 4;
  const int rsw = ((r15 >> 1) & 3) << 4;
  int aoff[8][2], boff[4][2];
#pragma unroll
  for (int fi = 0; fi < 8; ++fi) {
    int byte = ((wm * 128 + fi * 16 + r15) * 64 + hi * 16) ^ rsw;
#pragma unroll
    for (int ks = 0; ks < 2; ++ks) aoff[fi][ks] = ks * 8192 + (byte >> 1);
  }
#pragma unroll
  for (int fj = 0; fj < 4; ++fj) {
    int byte = ((wn * 64 + fj * 16 + r15) * 64 + hi * 16) ^ rsw;
#pragma unroll
    for (int ks = 0; ks < 2; ++ks) boff[fj][ks] = 16384 + ks * 8192 + (byte >> 1);
  }

  f32x4 acc[8][4] = {};

  // stage one half-tile (op, kh) of K-tile tgt into buffer dd
#define STG(dd, op, kh, tgt)                                                    \
  if ((tgt) < NT) {                                                             \
    unsigned short* dst_ = (unsigned short*)lds + (dd) * 32768 + (op) * 16384 + \
                           (kh) * 8192 + w * 1024;                              \
    async_ld16(sp[op][kh][0] + (tgt) * BK, dst_);                               \
    async_ld16(sp[op][kh][1] + (tgt) * BK, dst_ + 512);                         \
  }

  // VAR0 phase: reads (fiH=H_, ks=KS_) then STAGE, optional mid-barrier, MFMA
#define PHASE(H_, KS_, MIDBAR, STAGE_STMT)                                      \
  {                                                                             \
    bf16x8 af[4], bfr[4];                                                       \
    _Pragma("unroll") for (int i = 0; i < 4; ++i)                               \
        af[i] = *(const bf16x8*)&lb[aoff[(H_) * 4 + i][KS_]];                   \
    _Pragma("unroll") for (int j = 0; j < 4; ++j)                               \
        bfr[j] = *(const bf16x8*)&lb[boff[j][KS_]];                             \
    STAGE_STMT;                                                                 \
    if (MIDBAR) __builtin_amdgcn_s_barrier();                                   \
    asm volatile("s_waitcnt lgkmcnt(0)" ::: "memory");                          \
    __builtin_amdgcn_sched_barrier(0);                                          \
    __builtin_amdgcn_s_setprio(1);                                              \
    _Pragma("unroll") for (int i = 0; i < 4; ++i)                               \
      _Pragma("unroll") for (int j = 0; j < 4; ++j)                             \
        acc[(H_) * 4 + i][j] = __builtin_amdgcn_mfma_f32_16x16x32_bf16(         \
            af[i], bfr[j], acc[(H_) * 4 + i][j], 0, 0, 0);                      \
    __builtin_amdgcn_s_setprio(0);                                              \
    __builtin_amdgcn_s_barrier();                                               \
  }

  // VAR1 half-phase: A-reads only (B held), MFMA into acc rows H_*4..H_*4+3
#define PHASE_AHELD(H_, KS_, BREG, MIDBAR, STAGE_STMT)                          \
  {                                                                             \
    bf16x8 af[4];                                                               \
    _Pragma("unroll") for (int i = 0; i < 4; ++i)                               \
        af[i] = *(const bf16x8*)&lb[aoff[(H_) * 4 + i][KS_]];                   \
    STAGE_STMT;                                                                 \
    if (MIDBAR) __builtin_amdgcn_s_barrier();                                   \
    asm volatile("s_waitcnt lgkmcnt(0)" ::: "memory");                          \
    __builtin_amdgcn_sched_barrier(0);                                          \
    __builtin_amdgcn_s_setprio(1);                                              \
    _Pragma("unroll") for (int i = 0; i < 4; ++i)                               \
      _Pragma("unroll") for (int j = 0; j < 4; ++j)                             \
        acc[(H_) * 4 + i][j] = __builtin_amdgcn_mfma_f32_16x16x32_bf16(         \
            af[i], BREG[j], acc[(H_) * 4 + i][j], 0, 0, 0);                     \
    __builtin_amdgcn_s_setprio(0);                                              \
    __builtin_amdgcn_s_barrier();                                               \
  }

  // prologue: halves 0..5 = tile0{A0,B0,A1,B1} + tile1{A0,B0}  (12 loads/wave)
  STG(0, 0, 0, 0); STG(0, 1, 0, 0); STG(0, 0, 1, 0); STG(0, 1, 1, 0);
  STG(1, 0, 0, 1); STG(1, 1, 0, 1);

#pragma unroll
  for (int t = 0; t < NT; ++t) {
    const int d = t & 1;
    const unsigned short* lb = (const unsigned short*)lds + d * 32768;
    // tile boundary: wait tile t's 4 halves landed (2 halves may stay in flight)
    if (t == NT - 1) {
      asm volatile("s_waitcnt vmcnt(0)" ::: "memory");
    } else {
      asm volatile("s_waitcnt vmcnt(4)" ::: "memory");
    }
    __builtin_amdgcn_s_barrier();
    if constexpr (VAR == 0) {
      PHASE(0, 0, 0, STG(d ^ 1, 0, 1, t + 1));
      PHASE(1, 0, 1, STG(d ^ 1, 1, 1, t + 1));
      PHASE(0, 1, 1, STG(d, 0, 0, t + 2));
      PHASE(1, 1, 1, STG(d, 1, 0, t + 2));
    } else {
      // B-fragments read once per ks, held across both fiH phases
      bf16x8 b0[4], b1[4];
#pragma unroll
      for (int j = 0; j < 4; ++j) b0[j] = *(const bf16x8*)&lb[boff[j][0]];
      PHASE_AHELD(0, 0, b0, 0, STG(d ^ 1, 0, 1, t + 1));
      PHASE_AHELD(1, 0, b0, 1, STG(d ^ 1, 1, 1, t + 1));
#pragma unroll
      for (int j = 0; j < 4; ++j) b1[j] = *(const bf16x8*)&lb[boff[j][1]];
      PHASE_AHELD(0, 1, b1, 1, STG(d, 0, 0, t + 2));
      PHASE_AHELD(1, 1, b1, 1, STG(d, 1, 0, t + 2));
    }
  }
#undef PHASE
#undef PHASE_AHELD
#undef STG

  // ---- epilogue: D mapping col=lane&15, row=(lane>>4)*4+q ----
  const int or0 = hi * 4;
#pragma unroll
  for (int fi = 0; fi < 8; ++fi) {
#pragma unroll
    for (int fj = 0; fj < 4; ++fj) {
      const int col = n0 + wn * 64 + fj * 16 + r15;
      const int rowb = m0 + wm * 128 + fi * 16 + or0;
      float cb = BIAS_ROW ? 0.0f : bias[col];
#pragma unroll
      for (int q = 0; q < 4; ++q) {
        const int row = rowb + q;
        float v = acc[fi][fj][q] + (BIAS_ROW ? bias[row] : cb);
        if constexpr (C_BF16) {
          ((unsigned short*)Cv)[(size_t)sC * z + (size_t)row * ldc + col] = f2bf(v);
        } else {
          ((float*)Cv)[(size_t)sC * z + (size_t)row * ldc + col] = v;
        }
      }
    }
  }
}

// ------------- chunked mixer scan -------------
__global__ __launch_bounds__(256) void scan_carry(const unsigned short* __restrict__ proj,
                                                  float* __restrict__ carry,
                                                  const float* __restrict__ mix_w,
                                                  const float* __restrict__ decay_v) {
  const int b = blockIdx.x >> 6;
  const int c = blockIdx.x & (NCH - 1);
  const int n0 = threadIdx.x * 4;
  const int h = n0 >> 7;
  const float d = fminf(fmaxf(decay_v[h], 0.9f), 1.0f);
  const float r = powf(d, 1.0f / (float)DECAYC);
  const bool colrep = h < (HEADS / 2);
  const u16x4* p = (const u16x4*)(proj + ((size_t)(b * SEQ + c * CHUNK)) * DIM + n0);
  const float* mw = mix_w + h * SEQ + c * CHUNK;
  float s0 = 0.f, s1 = 0.f, s2 = 0.f, s3 = 0.f;
#pragma unroll 8
  for (int t = 0; t < CHUNK; ++t) {
    u16x4 v = p[t * (DIM / 4)];
    float wi = colrep ? 1.0f : mw[t];
    s0 = s0 * r + bf2f(v[0]) * wi;
    s1 = s1 * r + bf2f(v[1]) * wi;
    s2 = s2 * r + bf2f(v[2]) * wi;
    s3 = s3 * r + bf2f(v[3]) * wi;
  }
  f32x4 out = {s0, s1, s2, s3};
  *(f32x4*)(carry + ((size_t)(b * NCH + c)) * DIM + n0) = out;
}

__global__ __launch_bounds__(256) void scan_prefix(float* __restrict__ carry,
                                                   const float* __restrict__ decay_v) {
  const int idx = blockIdx.x * 256 + threadIdx.x;
  const int b = idx >> 10;
  const int n = idx & 1023;
  const int h = n >> 7;
  const float d = fminf(fmaxf(decay_v[h], 0.9f), 1.0f);
  const float r = powf(d, 1.0f / (float)DECAYC);
  const float rL = powf(r, (float)CHUNK);
  float P = 0.0f;
  for (int c = 0; c < NCH; ++c) {
    float* p = carry + ((size_t)(b * NCH + c)) * DIM + n;
    float cc = *p;
    *p = P;
    P = rL * P + cc;
  }
}

__global__ __launch_bounds__(256) void scan_apply(const unsigned short* __restrict__ proj,
                                                  unsigned short* __restrict__ hidden,
                                                  const float* __restrict__ carry,
                                                  const float* __restrict__ mix_w,
                                                  const float* __restrict__ mix_b,
                                                  const float* __restrict__ decay_v) {
  const int b = blockIdx.x >> 6;
  const int c = blockIdx.x & (NCH - 1);
  const int n0 = threadIdx.x * 4;
  const int h = n0 >> 7;
  const float d = fminf(fmaxf(decay_v[h], 0.9f), 1.0f);
  const float r = powf(d, 1.0f / (float)DECAYC);
  const bool colrep = h < (HEADS / 2);
  const size_t base = ((size_t)(b * SEQ + c * CHUNK)) * DIM + n0;
  const u16x4* p = (const u16x4*)(proj + base);
  u16x4* o = (u16x4*)(hidden + base);
  const float* mw = mix_w + h * SEQ + c * CHUNK;
  const float* mb = mix_b + h * SEQ + c * CHUNK;
  f32x4 ci = *(const f32x4*)(carry + ((size_t)(b * NCH + c)) * DIM + n0);
  float s0 = ci[0], s1 = ci[1], s2 = ci[2], s3 = ci[3];
#pragma unroll 8
  for (int t = 0; t < CHUNK; ++t) {
    u16x4 v = p[t * (DIM / 4)];
    float wv = mw[t];
    float wi = colrep ? 1.0f : wv;
    float wo = colrep ? wv : 1.0f;
    float bb = mb[t];
    s0 = s0 * r + bf2f(v[0]) * wi;
    s1 = s1 * r + bf2f(v[1]) * wi;
    s2 = s2 * r + bf2f(v[2]) * wi;
    s3 = s3 * r + bf2f(v[3]) * wi;
    u16x4 ov;
    ov[0] = f2bf(s0 * wo + bb);
    ov[1] = f2bf(s1 * wo + bb);
    ov[2] = f2bf(s2 * wo + bb);
    ov[3] = f2bf(s3 * wo + bb);
    o[t * (DIM / 4)] = ov;
  }
}

extern "C" void kernel_launch(void* const* d_in, const int* in_sizes, int n_in,
                              void* d_out, int out_size, void* d_ws, size_t ws_size,
                              hipStream_t stream) {
  const float* x = (const float*)d_in[0];
  const float* proj_w = (const float*)d_in[1];
  const float* proj_b = (const float*)d_in[2];
  const float* mix_w = (const float*)d_in[3];
  const float* mix_b = (const float*)d_in[4];
  const float* decay_v = (const float*)d_in[5];
  const float* out_w = (const float*)d_in[6];
  const float* out_b = (const float*)d_in[7];

  char* ws = (char*)d_ws;
  unsigned short* xT = (unsigned short*)ws;                // 33.5 MB (B*T, E) bf16
  unsigned short* proj = (unsigned short*)(ws + 33554432); // 33.5 MB (B*T, N) bf16
  unsigned short* W1 = (unsigned short*)(ws + 67108864);   // 2 MB (dead after GEMM1)
  unsigned short* W2 = (unsigned short*)(ws + 69206016);   // 2 MB
  unsigned short* hidden = xT;                             // reuse: xT dead after GEMM1
  float* carryf = (float*)(ws + 67108864);                 // 2 MB, overlaps W1 (dead)

  const int NW = DIM * DIM;
  convertk2<<<dim3((NW + 255) / 256), 256, 0, stream>>>(proj_w, W1, out_w, W2, NW);
  transpose_x<<<dim3(16, 32, 8), 256, 0, stream>>>(x, xT);

  // GEMM1 (VAR=1, B-held A/B arm): proj = xT . W1^T + proj_b
  gemm256<1, 0, 1, 1><<<dim3(256), 512, 0, stream>>>(xT, W1, proj, proj_b, DIM, 0L, 0L);

  // chunked mixer scan
  scan_carry<<<dim3(8 * NCH), 256, 0, stream>>>(proj, carryf, mix_w, decay_v);
  scan_prefix<<<dim3(8192 / 256), 256, 0, stream>>>(carryf, decay_v);
  scan_apply<<<dim3(8 * NCH), 256, 0, stream>>>(proj, hidden, carryf, mix_w, mix_b, decay_v);

  // GEMM2 (VAR=0, exact-R4 control arm): out[b] = W2 . hidden[b]^T + out_b
  gemm256<0, 1, 2, 0><<<dim3(256), 512, 0, stream>>>(W2, hidden, d_out, out_b, SEQ,
                                                     (long)SEQ * DIM, (long)DIM * SEQ);
}